// Round 10
// baseline (243.278 us; speedup 1.0000x reference)
//
#include <hip/hip_runtime.h>
#include <stdint.h>

typedef unsigned short u16;
typedef float v4f __attribute__((ext_vector_type(4)));
typedef short v8s __attribute__((ext_vector_type(8)));

#define B_   8192
#define IN_  1024
#define OUT_ 1024
#define D_   8

#define BM 256
#define BN 128
#define BK 64             // K-tile: 2 sub-phases of 16 MFMA each

__device__ __forceinline__ u16 f2bf(float f) {
  uint32_t u = __float_as_uint(f);
  u += 0x7fffu + ((u >> 16) & 1u);   // RTNE (inputs finite)
  return (u16)(u >> 16);
}

// ---- prep: input + weights f32 -> bf16 (proven) ----------------------------
__global__ __launch_bounds__(256) void convert_both(
    const float* __restrict__ input, const float* __restrict__ weights,
    u16* __restrict__ inBf, u16* __restrict__ wtBf) {
  int i4 = blockIdx.x * blockDim.x + threadIdx.x;
  const int n4 = (B_ * IN_) / 4;
  const float* src;
  u16* dst;
  int idx;
  if (i4 < n4) { src = input;   dst = inBf; idx = i4; }
  else         { src = weights; dst = wtBf; idx = i4 - n4; }
  float4 v = ((const float4*)src)[idx];
  ushort4 o;
  o.x = f2bf(v.x); o.y = f2bf(v.y); o.z = f2bf(v.z); o.w = f2bf(v.w);
  ((ushort4*)dst)[idx] = o;
}

__device__ __forceinline__ void gload_lds16(const u16* g, u16* l) {
  typedef __attribute__((address_space(1))) void gvoid;
  typedef __attribute__((address_space(3))) void lvoid;
  __builtin_amdgcn_global_load_lds((gvoid*)g, (lvoid*)l, 16, 0, 0);
}

// ---- 8-wave 2-sub-phase GEMM (faithful m201-template port) -----------------
// R9 calibration: R6's 43% MfmaUtil is a SCHEDULE limit (m233: 2-phase
// critical path = stage+vmcnt+barrier), not LDS BW (m134's 12cyc/b128 is
// single-wave issue cost; multi-wave reads overlap -- else m201 could never
// hit 62%). The proven fix is the phase-split schedule (T3+T4, m230 gate).
// R5 tried this but its A ds_write staging polluted every phase's lgkmcnt(0)
// gate; telescoping rescale (R6) makes A plain bf16 -> ALL staging is
// global_load_lds -> first faithful port:
//   per K-tile: 2 sub-phases, each {8 ds_read_b128 | 2-4 gload_lds | barrier
//   | lgkmcnt(0)+sched_barrier | setprio(1) 16 MFMA setprio(0) | barrier};
//   counted vmcnt(2) once per tile (never 0 in-loop).
// Geometry: BM=256 x BN=128, 512 thr (8 waves, 4M x 2N, per-wave 64x64 --
// fragments/epilogue/rescale identical to R6), 256 blocks = 1/CU,
// LDS = A 2x32KB + B 4x16KB = 128 KB. Occupancy 8 waves/CU = 2/SIMD (same
// as R6), but one barrier domain -> per-phase wave role-split (T5 prereq).
// Branch-free body: A-slice wraps mod 16 (A is dd-independent, so the wrap
// stages exactly the next plane's first slice -- zero waste); B wraps into
// dead buffers at t>=126 (written, never read).
// vmcnt ledger (uniform): tile t issues A(t+1)x4 (ph0:2, ph1:2) THEN
// B(t+2)x2 (ph1); end-of-tile queue [B(t+1)2, A(t+1)4, B(t+2)2] ->
// vmcnt(2) completes B(t+1)+A(t+1), leaves B(t+2). Prologue: [A0x4, B0x2,
// B1x2] -> vmcnt(2). No edge cases.
__global__ __launch_bounds__(512, 2) void gemm_8w(
    const u16* __restrict__ A,        // [B_][IN_] bf16 input (unscaled)
    const u16* __restrict__ Wt,       // [D_][OUT_][IN_] bf16
    const float* __restrict__ w,      // [B_][D_]
    const float* __restrict__ biases, // [D_][OUT_]
    float* __restrict__ out) {        // [B_][OUT_]
  __shared__ __align__(16) u16 As[2][BM * BK];   // 64 KB
  __shared__ __align__(16) u16 Bs[4][BN * BK];   // 64 KB

  const int id   = blockIdx.x;                // 256 blocks (1/CU)
  const int xcd  = id & 7;
  const int slot = id >> 3;                   // 0..31
  const int by   = xcd + ((slot & 3) << 3);   // 0..31 (R6-style co-XCD groups)
  const int bx   = slot >> 2;                 // 0..7

  const int tid  = threadIdx.x;               // 0..511
  const int wid  = tid >> 6;                  // 0..7
  const int lane = tid & 63;
  const int wr   = wid >> 1, wc = wid & 1;    // 4M x 2N wave grid
  const int quad = lane >> 4, l16 = lane & 15;
  const int m0   = by * BM;
  const int n0   = bx * BN;

  // staging: chunk c = j*512 + tid; row = c>>3 = j*64 + (tid>>3);
  // LDS chunk (c&7) of row holds global chunk swz = (c&7)^(row&7) (j-invar.)
  const int swz  = (tid & 7) ^ ((tid >> 3) & 7);
  const int rowT = tid >> 3;                  // 0..63
  const u16* aBase[4];
  const u16* bBase[2];
  int aOff[4], bOff[2];
#pragma unroll
  for (int j = 0; j < 4; ++j) {
    aBase[j] = A + (size_t)(m0 + j * 64 + rowT) * IN_ + swz * 8;
    aOff[j]  = (j * 512 + tid) * 8;
  }
#pragma unroll
  for (int j = 0; j < 2; ++j) {
    bBase[j] = Wt + (size_t)(n0 + j * 64 + rowT) * IN_ + swz * 8;
    bOff[j]  = (j * 512 + tid) * 8;
  }

  // fragment LDS offsets (u16 index), de-swizzled (identical to R6)
  const int aRow = wr * 64 + l16;             // 0..255
  const int bRow = wc * 64 + l16;             // 0..127
  const int e    = l16 & 7;
  int aCol[2];
#pragma unroll
  for (int h = 0; h < 2; ++h) aCol[h] = ((quad + 4 * h) ^ e) * 8;

  const v4f vzero = {0.f, 0.f, 0.f, 0.f};
  v4f acc[4][4];
#pragma unroll
  for (int mt = 0; mt < 4; ++mt)
#pragma unroll
    for (int nt = 0; nt < 4; ++nt) acc[mt][nt] = vzero;

  // wp[mt][r] = g(w[row, current plane]); init plane 0 (telescoping rescale)
  float wp[4][4];
#pragma unroll
  for (int mt = 0; mt < 4; ++mt)
#pragma unroll
    for (int r = 0; r < 4; ++r) {
      const int grow = m0 + wr * 64 + mt * 16 + quad * 4 + r;
      wp[mt][r] = fmaxf(w[(size_t)grow * D_], 1e-30f);
    }

  // ---- prologue: A(it0) -> As[0]; B(t0) -> Bs[0]; B(t1) -> Bs[1]
#pragma unroll
  for (int j = 0; j < 4; ++j) gload_lds16(aBase[j], &As[0][aOff[j]]);
#pragma unroll
  for (int j = 0; j < 2; ++j) gload_lds16(bBase[j], &Bs[0][bOff[j]]);
#pragma unroll
  for (int j = 0; j < 2; ++j)
    gload_lds16(bBase[j] + (size_t)BK, &Bs[1][bOff[j]]);  // (dd0, it1)
  asm volatile("s_waitcnt vmcnt(2) lgkmcnt(0)" ::: "memory");
  __builtin_amdgcn_s_barrier();

  // ---- main: dd outer (7 rescale interludes), it = ip*4+u (u unrolled:
  // A buf = u&1, B buf = u, all static)
  for (int dd = 0; dd < D_; ++dd) {
    if (dd > 0) {
#pragma unroll
      for (int mt = 0; mt < 4; ++mt) {
#pragma unroll
        for (int r = 0; r < 4; ++r) {
          const int grow = m0 + wr * 64 + mt * 16 + quad * 4 + r;
          const float wn = fmaxf(w[(size_t)grow * D_ + dd], 1e-30f);
          const float ratio = wp[mt][r] / wn;
          wp[mt][r] = wn;
#pragma unroll
          for (int nt = 0; nt < 4; ++nt) acc[mt][nt][r] *= ratio;
        }
      }
    }
    for (int ip = 0; ip < 4; ++ip) {
#pragma unroll
      for (int u = 0; u < 4; ++u) {
        const int it  = ip * 4 + u;
        const int kA  = u & 1;                 // static
        const int kAn = kA ^ 1;
        const int kB  = u;                     // static
        const int kBs = (u + 2) & 3;           // static
        const int sit = (it + 1) & 15;         // A slice for t+1 (dd-invar.)
        const int su  = dd * 16 + it + 2;      // B tile t+2 (wraps harmless)
        const size_t bo = (size_t)((su >> 4) & 7) * (OUT_ * IN_) +
                          (size_t)(su & 15) * BK;

        // ============ sub-phase 0 (h=0) ============
        {
          v8s af[4], bf[4];
#pragma unroll
          for (int mt = 0; mt < 4; ++mt)
            af[mt] = *(const v8s*)(&As[kA][(aRow + mt * 16) * BK + aCol[0]]);
#pragma unroll
          for (int nt = 0; nt < 4; ++nt)
            bf[nt] = *(const v8s*)(&Bs[kB][(bRow + nt * 16) * BK + aCol[0]]);
          gload_lds16(aBase[0] + sit * BK, &As[kAn][aOff[0]]);
          gload_lds16(aBase[1] + sit * BK, &As[kAn][aOff[1]]);
          __builtin_amdgcn_s_barrier();
          asm volatile("s_waitcnt lgkmcnt(0)" ::: "memory");
          __builtin_amdgcn_sched_barrier(0);
          __builtin_amdgcn_s_setprio(1);
#pragma unroll
          for (int mt = 0; mt < 4; ++mt)
#pragma unroll
            for (int nt = 0; nt < 4; ++nt)
              acc[mt][nt] = __builtin_amdgcn_mfma_f32_16x16x32_bf16(
                  af[mt], bf[nt], acc[mt][nt], 0, 0, 0);
          __builtin_amdgcn_s_setprio(0);
          __builtin_amdgcn_s_barrier();
        }

        // ============ sub-phase 1 (h=1) ============
        {
          v8s af[4], bf[4];
#pragma unroll
          for (int mt = 0; mt < 4; ++mt)
            af[mt] = *(const v8s*)(&As[kA][(aRow + mt * 16) * BK + aCol[1]]);
#pragma unroll
          for (int nt = 0; nt < 4; ++nt)
            bf[nt] = *(const v8s*)(&Bs[kB][(bRow + nt * 16) * BK + aCol[1]]);
          gload_lds16(aBase[2] + sit * BK, &As[kAn][aOff[2]]);
          gload_lds16(aBase[3] + sit * BK, &As[kAn][aOff[3]]);
          gload_lds16(bBase[0] + bo, &Bs[kBs][bOff[0]]);
          gload_lds16(bBase[1] + bo, &Bs[kBs][bOff[1]]);
          __builtin_amdgcn_s_barrier();
          asm volatile("s_waitcnt lgkmcnt(0)" ::: "memory");
          __builtin_amdgcn_sched_barrier(0);
          __builtin_amdgcn_s_setprio(1);
#pragma unroll
          for (int mt = 0; mt < 4; ++mt)
#pragma unroll
            for (int nt = 0; nt < 4; ++nt)
              acc[mt][nt] = __builtin_amdgcn_mfma_f32_16x16x32_bf16(
                  af[mt], bf[nt], acc[mt][nt], 0, 0, 0);
          __builtin_amdgcn_s_setprio(0);
          // counted end-of-tile wait: B(t+1)+A(t+1) done, B(t+2) in flight
          asm volatile("s_waitcnt vmcnt(2)" ::: "memory");
          __builtin_amdgcn_s_barrier();
        }
      }
    }
  }

  // ---- epilogue: out = acc * g(w[:,7]) + sum_d w[b,d]*biases[d,o]
  float bcol[4][8];
#pragma unroll
  for (int nt = 0; nt < 4; ++nt) {
    const int col = n0 + wc * 64 + nt * 16 + l16;
#pragma unroll
    for (int dd = 0; dd < 8; ++dd) bcol[nt][dd] = biases[dd * OUT_ + col];
  }
#pragma unroll
  for (int mt = 0; mt < 4; ++mt) {
#pragma unroll
    for (int r = 0; r < 4; ++r) {
      const int grow = m0 + wr * 64 + mt * 16 + quad * 4 + r;
      const v4f* wpg = (const v4f*)(w + (size_t)grow * D_);
      const v4f wa = wpg[0], wb = wpg[1];
      const float wlast = wp[mt][r];
#pragma unroll
      for (int nt = 0; nt < 4; ++nt) {
        const int col = n0 + wc * 64 + nt * 16 + l16;
        const float bias = wa[0] * bcol[nt][0] + wa[1] * bcol[nt][1] +
                           wa[2] * bcol[nt][2] + wa[3] * bcol[nt][3] +
                           wb[0] * bcol[nt][4] + wb[1] * bcol[nt][5] +
                           wb[2] * bcol[nt][6] + wb[3] * bcol[nt][7];
        out[(size_t)grow * OUT_ + col] = acc[mt][nt][r] * wlast + bias;
      }
    }
  }
}

extern "C" void kernel_launch(void* const* d_in, const int* in_sizes, int n_in,
                              void* d_out, int out_size, void* d_ws, size_t ws_size,
                              hipStream_t stream) {
  const float* input   = (const float*)d_in[0];
  const float* w       = (const float*)d_in[1];
  const float* weights = (const float*)d_in[2];
  const float* biases  = (const float*)d_in[3];
  float* out = (float*)d_out;

  u16* inBf = (u16*)d_ws;                               // 16 MB
  u16* wtBf = inBf + (size_t)B_ * IN_;                  // 16 MB

  const int totalF4 = (B_ * IN_ + D_ * OUT_ * IN_) / 4;
  convert_both<<<dim3(totalF4 / 256), 256, 0, stream>>>(input, weights, inBf, wtBf);
  gemm_8w<<<dim3(256), 512, 0, stream>>>(inBf, wtBf, w, biases, out);
}

// Round 11
// 237.333 us; speedup vs baseline: 1.0251x; 1.0251x over previous
//
#include <hip/hip_runtime.h>
#include <stdint.h>

typedef unsigned short u16;
typedef float v4f __attribute__((ext_vector_type(4)));
typedef short v8s __attribute__((ext_vector_type(8)));

#define B_   8192
#define IN_  1024
#define OUT_ 1024
#define D_   8

#define BM 128
#define BN 128
#define BK 64             // K-tile per phase: 32 MFMAs, 1 barrier

__device__ __forceinline__ u16 f2bf(float f) {
  uint32_t u = __float_as_uint(f);
  u += 0x7fffu + ((u >> 16) & 1u);   // RTNE (inputs finite)
  return (u16)(u >> 16);
}

// ---- prep: input + weights f32 -> bf16 (proven) ----------------------------
__global__ __launch_bounds__(256) void convert_both(
    const float* __restrict__ input, const float* __restrict__ weights,
    u16* __restrict__ inBf, u16* __restrict__ wtBf) {
  int i4 = blockIdx.x * blockDim.x + threadIdx.x;
  const int n4 = (B_ * IN_) / 4;
  const float* src;
  u16* dst;
  int idx;
  if (i4 < n4) { src = input;   dst = inBf; idx = i4; }
  else         { src = weights; dst = wtBf; idx = i4 - n4; }
  float4 v = ((const float4*)src)[idx];
  ushort4 o;
  o.x = f2bf(v.x); o.y = f2bf(v.y); o.z = f2bf(v.z); o.w = f2bf(v.w);
  ((ushort4*)dst)[idx] = o;
}

__device__ __forceinline__ void gload_lds16(const u16* g, u16* l) {
  typedef __attribute__((address_space(1))) void gvoid;
  typedef __attribute__((address_space(3))) void lvoid;
  __builtin_amdgcn_global_load_lds((gvoid*)g, (lvoid*)l, 16, 0, 0);
}

// ---- GEMM with telescoping accumulator rescale (R6, empirical best) --------
// out[b,o] = sum_d w[b,d] * (input[b,:] . weights[d,o,:]) + bias-term.
// ONE accumulator bank with invariant "acc is in units of 1/g(w[row,dd_cur])":
//   at plane boundary: acc *= g(w[row,prev]) / g(w[row,next])   (7 interludes)
//   epilogue:          out  = acc * g(w[row,7]) + bias
// g(x)=max(x,1e-30) guards w==0. K-loop is pure gload_lds staging (A 4 + B 4
// per tile, no ds_write/cvt/f32 loads) + counted-vmcnt single-barrier tiles.
// vmcnt ledger (4 loads per issue-group, FIFO):
//   top of t: issue A(t+1) then B(t+2); queue [B(t+1), A(t+1), B(t+2)]
//   end of t: need B(t+1)+A(t+1) -> vmcnt(4).  t==126: vmcnt(0).  t==127: none.
// Session evidence (11 rounds): this structure beats every alternative tried:
//   R1 second acc bank (occupancy kill), R2 in-phase reg-staging (Mfma 28%),
//   R4 triple-buffer+counted-vmcnt on 2-barrier (null), R5 4-wave phase-split
//   (-46%), R7 full static unroll (-15%), R8 A-frags direct from global
//   (-13%), R10 8-wave faithful phase-split port (-14%).
//   = m97-family ceiling: 142 us counter-time, 967 TF, 43.5% MfmaUtil.
__global__ __launch_bounds__(256, 2) void gemm_rs(
    const u16* __restrict__ A,        // [B_][IN_] bf16 input (unscaled)
    const u16* __restrict__ Wt,       // [D_][OUT_][IN_] bf16
    const float* __restrict__ w,      // [B_][D_]
    const float* __restrict__ biases, // [D_][OUT_]
    float* __restrict__ out) {        // [B_][OUT_]
  __shared__ __align__(16) u16 As[2][BM * BK];   // 32 KB
  __shared__ __align__(16) u16 Bs[3][BN * BK];   // 48 KB -> 80 KB: 2 blk/CU

  // R0-proven mapping: all 8 blocks sharing an A-panel are co-XCD.
  const int id   = blockIdx.x;                // 512 blocks
  const int xcd  = id & 7;
  const int slot = id >> 3;
  const int by   = xcd + ((slot & 7) << 3);   // 0..63
  const int bx   = slot >> 3;                 // 0..7

  const int tid  = threadIdx.x;
  const int wid  = tid >> 6;
  const int lane = tid & 63;
  const int wr   = wid >> 1, wc = wid & 1;
  const int quad = lane >> 4, l16 = lane & 15;
  const int m0   = by * BM;
  const int n0   = bx * BN;

  // staging geometry (proven): chunk c = wid*256+j*64+lane; row = c>>3;
  // LDS chunk (lane&7) holds global chunk swz = (lane&7)^((lane>>3)&7).
  const int swz  = (lane & 7) ^ ((lane >> 3) & 7);
  const int rowS = wid * 32 + (lane >> 3);    // + j*8
  const u16* aBase[4];
  const u16* bBase[4];
  int cOff[4];
#pragma unroll
  for (int j = 0; j < 4; ++j) {
    const int row = rowS + j * 8;
    aBase[j] = A  + (size_t)(m0 + row) * IN_ + swz * 8;
    bBase[j] = Wt + (size_t)(n0 + row) * IN_ + swz * 8;
    cOff[j]  = (wid * 256 + j * 64 + lane) * 8;
  }

  // fragment LDS offsets (u16 index), de-swizzled
  const int aRow = wr * 64 + l16;
  const int bRow = wc * 64 + l16;
  const int e    = l16 & 7;
  int aCol[2];
#pragma unroll
  for (int h = 0; h < 2; ++h) aCol[h] = ((quad + 4 * h) ^ e) * 8;

  const v4f vzero = {0.f, 0.f, 0.f, 0.f};
  v4f acc[4][4];
#pragma unroll
  for (int mt = 0; mt < 4; ++mt)
#pragma unroll
    for (int nt = 0; nt < 4; ++nt) acc[mt][nt] = vzero;

  // wp[mt][r] = g(w[row, current plane]); init plane 0
  float wp[4][4];
#pragma unroll
  for (int mt = 0; mt < 4; ++mt)
#pragma unroll
    for (int r = 0; r < 4; ++r) {
      const int grow = m0 + wr * 64 + mt * 16 + quad * 4 + r;
      wp[mt][r] = fmaxf(w[(size_t)grow * D_], 1e-30f);
    }

  // rotating buffers
  u16* aC_ = As[0];
  u16* aN  = As[1];
  u16* bC  = Bs[0];
  u16* bN  = Bs[1];
  u16* bS  = Bs[2];

  // ---- prologue: A(slice 0) -> aC_, B(t=0) -> bC, B(t=1) -> bN
#pragma unroll
  for (int j = 0; j < 4; ++j) gload_lds16(aBase[j], aC_ + cOff[j]);
#pragma unroll
  for (int j = 0; j < 4; ++j) gload_lds16(bBase[j], bC + cOff[j]);
#pragma unroll
  for (int j = 0; j < 4; ++j)
    gload_lds16(bBase[j] + (size_t)BK, bN + cOff[j]);   // (dd0, it1)
  asm volatile("s_waitcnt vmcnt(4) lgkmcnt(0)" ::: "memory"); // A0+B0 done
  __builtin_amdgcn_s_barrier();

  // ---- main: dd outer (7 cheap rescale interludes), it inner, t = dd*16+it
  for (int dd = 0; dd < D_; ++dd) {
    if (dd > 0) {
      // plane transition: acc *= g(w[:,dd-1]) / g(w[:,dd])
#pragma unroll
      for (int mt = 0; mt < 4; ++mt) {
#pragma unroll
        for (int r = 0; r < 4; ++r) {
          const int grow = m0 + wr * 64 + mt * 16 + quad * 4 + r;
          const float wn = fmaxf(w[(size_t)grow * D_ + dd], 1e-30f);
          const float ratio = wp[mt][r] / wn;
          wp[mt][r] = wn;
#pragma unroll
          for (int nt = 0; nt < 4; ++nt) acc[mt][nt][r] *= ratio;
        }
      }
    }
    for (int it = 0; it < 16; ++it) {
      const int t = dd * 16 + it;

      // -- stage A slice (t+1), 1-ahead (A independent of dd; slice wraps)
      if (t < 127) {
        const int sit = (it + 1) & 15;
#pragma unroll
        for (int j = 0; j < 4; ++j)
          gload_lds16(aBase[j] + sit * BK, aN + cOff[j]);
      }
      // -- stage B tile (t+2), 2-ahead (issued AFTER A: keeps A older in FIFO)
      if (t < 126) {
        const int it2  = it + 2;
        const int sdd2 = dd + (it2 >> 4);
        const int sit2 = it2 & 15;
#pragma unroll
        for (int j = 0; j < 4; ++j)
          gload_lds16(bBase[j] + (size_t)sdd2 * (OUT_ * IN_) + sit2 * BK,
                      bS + cOff[j]);
      }

      // -- compute on aC_, bC
      __builtin_amdgcn_s_setprio(1);
#pragma unroll
      for (int h = 0; h < 2; ++h) {
        v8s af[4], bf[4];
#pragma unroll
        for (int mt = 0; mt < 4; ++mt)
          af[mt] = *(const v8s*)(aC_ + (aRow + mt * 16) * BK + aCol[h]);
#pragma unroll
        for (int nt = 0; nt < 4; ++nt)
          bf[nt] = *(const v8s*)(bC + (bRow + nt * 16) * BK + aCol[h]);
#pragma unroll
        for (int mt = 0; mt < 4; ++mt)
#pragma unroll
          for (int nt = 0; nt < 4; ++nt)
            acc[mt][nt] = __builtin_amdgcn_mfma_f32_16x16x32_bf16(
                af[mt], bf[nt], acc[mt][nt], 0, 0, 0);
      }
      __builtin_amdgcn_s_setprio(0);

      // -- counted wait + barrier
      if (t < 126) {
        asm volatile("s_waitcnt vmcnt(4)" ::: "memory");  // B(t+1)+A(t+1) done
        __builtin_amdgcn_s_barrier();
      } else if (t == 126) {
        asm volatile("s_waitcnt vmcnt(0)" ::: "memory");  // drain for last tile
        __builtin_amdgcn_s_barrier();
      }

      // -- rotate buffers
      u16* ta = aC_; aC_ = aN; aN = ta;
      u16* tb = bC; bC = bN; bN = bS; bS = tb;
    }
  }

  // ---- epilogue: out = acc * g(w[:,7]) + sum_d w[b,d]*biases[d,o]
  float bcol[4][8];
#pragma unroll
  for (int nt = 0; nt < 4; ++nt) {
    const int col = n0 + wc * 64 + nt * 16 + l16;
#pragma unroll
    for (int dd = 0; dd < 8; ++dd) bcol[nt][dd] = biases[dd * OUT_ + col];
  }
#pragma unroll
  for (int mt = 0; mt < 4; ++mt) {
#pragma unroll
    for (int r = 0; r < 4; ++r) {
      const int grow = m0 + wr * 64 + mt * 16 + quad * 4 + r;
      const v4f* wpg = (const v4f*)(w + (size_t)grow * D_);
      const v4f wa = wpg[0], wb = wpg[1];
      const float wlast = wp[mt][r];
#pragma unroll
      for (int nt = 0; nt < 4; ++nt) {
        const int col = n0 + wc * 64 + nt * 16 + l16;
        const float bias = wa[0] * bcol[nt][0] + wa[1] * bcol[nt][1] +
                           wa[2] * bcol[nt][2] + wa[3] * bcol[nt][3] +
                           wb[0] * bcol[nt][4] + wb[1] * bcol[nt][5] +
                           wb[2] * bcol[nt][6] + wb[3] * bcol[nt][7];
        out[(size_t)grow * OUT_ + col] = acc[mt][nt][r] * wlast + bias;
      }
    }
  }
}

extern "C" void kernel_launch(void* const* d_in, const int* in_sizes, int n_in,
                              void* d_out, int out_size, void* d_ws, size_t ws_size,
                              hipStream_t stream) {
  const float* input   = (const float*)d_in[0];
  const float* w       = (const float*)d_in[1];
  const float* weights = (const float*)d_in[2];
  const float* biases  = (const float*)d_in[3];
  float* out = (float*)d_out;

  u16* inBf = (u16*)d_ws;                               // 16 MB
  u16* wtBf = inBf + (size_t)B_ * IN_;                  // 16 MB

  const int totalF4 = (B_ * IN_ + D_ * OUT_ * IN_) / 4;
  convert_both<<<dim3(totalF4 / 256), 256, 0, stream>>>(input, weights, inBf, wtBf);
  gemm_rs<<<dim3(512), 256, 0, stream>>>(inBf, wtBf, w, biases, out);
}